// Round 3
// baseline (148.873 us; speedup 1.0000x reference)
//
#include <hip/hip_runtime.h>
#include <stdint.h>

#define B_ROWS 8192
#define H_DIM 1024
#define L_DIM 1024
#define NH 5

typedef short bf16x8 __attribute__((ext_vector_type(8)));
typedef float f32x4 __attribute__((ext_vector_type(4)));

typedef const __attribute__((address_space(1))) unsigned int* gas_uint_ptr;
typedef __attribute__((address_space(3))) unsigned int* las_uint_ptr;

__device__ __forceinline__ unsigned short f2bf(float f) {
  union { float f; unsigned int u; } v; v.f = f;
  return (unsigned short)((v.u + 0x7FFFu + ((v.u >> 16) & 1u)) >> 16);
}

__device__ __forceinline__ void load_lds16(const void* gsrc, void* ldst) {
  __builtin_amdgcn_global_load_lds((gas_uint_ptr)(uintptr_t)gsrc,
                                   (las_uint_ptr)(uintptr_t)ldst, 16, 0, 0);
}

// ---- kernel 1: fused streaming convert + bucket (unchanged structure) ----
// blocks [0,512):     W fp32->bf16, grid-stride, 10 float4/thread (NT loads)
// blocks [512,1536):  8 rows/block; g==5 -> fill out with label, else hidden->bf16 Hb
// blocks [1536,1568): bucket rows by group (LDS-aggregated, 5 global atomics/block)
__global__ void k_conv(const float* __restrict__ hidden, const float* __restrict__ W,
                       const int* __restrict__ group, const int* __restrict__ labels,
                       int* __restrict__ cnt, int* __restrict__ rowlist,
                       unsigned short* __restrict__ Hb, unsigned short* __restrict__ Wb,
                       float* __restrict__ out) {
  const int blk = blockIdx.x;
  const int t = threadIdx.x;
  if (blk < 512) {
    const f32x4* src = (const f32x4*)W;
    ushort4* dst = (ushort4*)Wb;
#pragma unroll
    for (int i = 0; i < 10; i++) {
      int idx = (i * 512 + blk) * 256 + t;   // 512*256*10 = 1,310,720 float4 = all of W
      f32x4 w = __builtin_nontemporal_load(&src[idx]);  // read-once: keep L2 for Wb/Hb
      ushort4 o;
      o.x = f2bf(w.x); o.y = f2bf(w.y); o.z = f2bf(w.z); o.w = f2bf(w.w);
      dst[idx] = o;
    }
  } else if (blk < 1536) {
    const int rb = (blk - 512) * 8;
    int gs[8];
#pragma unroll
    for (int r = 0; r < 8; r++) gs[r] = group[rb + r];   // independent loads up front
#pragma unroll
    for (int r = 0; r < 8; r++) {
      int row = rb + r;
      if (gs[r] == NH) {
        float v = (float)labels[row];
        f32x4 fv; fv.x = v; fv.y = v; fv.z = v; fv.w = v;
        __builtin_nontemporal_store(fv, &((f32x4*)(out + (size_t)row * L_DIM))[t]);
      } else {
        f32x4 h = __builtin_nontemporal_load(&((const f32x4*)(hidden + (size_t)row * H_DIM))[t]);
        ushort4 o;
        o.x = f2bf(h.x); o.y = f2bf(h.y); o.z = f2bf(h.z); o.w = f2bf(h.w);
        ((ushort4*)(Hb + (size_t)row * H_DIM))[t] = o;
      }
    }
  } else {
    __shared__ int lcnt[NH];
    __shared__ int lbase[NH];
    if (t < NH) lcnt[t] = 0;
    __syncthreads();
    int b = (blk - 1536) * 256 + t;
    int g = group[b];
    int lpos = -1;
    if (g < NH) lpos = atomicAdd(&lcnt[g], 1);
    __syncthreads();
    if (t < NH) lbase[t] = atomicAdd(&cnt[t], lcnt[t]);
    __syncthreads();
    if (g < NH) rowlist[g * B_ROWS + lbase[g] + lpos] = b;
  }
}

// ---- kernel 2: bucketed bf16 MFMA GEMM, 128x256 tile (LDS-traffic-reduced) ----
// BM=128, BN=256, BK=64, double-buffered LDS (96 KB -> 1 block/CU), 4 waves
// arranged 2x2; each wave owns a 64x128 sub-tile = 4x8 frags of 16x16x32 bf16.
// Rationale: at the old 64x64 wave tile the kernel was LDS-BW paced
// (~192 KB LDS traffic per CU-Kstep vs ~1030 cyc of MFMA); the 64x128 wave
// tile cuts ds_read bytes/FLOP by 25% (12 reads feed 32 MFMAs) and block
// count 440->220 cuts staging traffic 25%. Prefetch kt+1 before computing kt:
// the barrier's vmcnt(0) drain has the whole ~1700-cyc MFMA+ds_read phase to
// complete, covering even HBM-miss latency at 1 block/CU.
// XOR swizzle unchanged: 16B chunk cl holds global chunk cl ^ (row&7).
__global__ __launch_bounds__(256, 1)
void k_gemm(const unsigned short* __restrict__ Hb, const unsigned short* __restrict__ Wb,
            const float* __restrict__ bias, const int* __restrict__ cnt,
            const int* __restrict__ rowlist, float* __restrict__ out) {
  const int head = blockIdx.z;
  const int cntg = cnt[head];
  const int rowbase = blockIdx.y * 128;
  if (rowbase >= cntg) return;
  const int n0 = blockIdx.x * 256;

  __shared__ __align__(16) unsigned short As[2][128 * 64];
  __shared__ __align__(16) unsigned short Bs[2][256 * 64];

  const int t = threadIdx.x;
  const int wave = t >> 6, lane = t & 63;
  const int quad = lane >> 4, c16 = lane & 15;
  const int wm = (wave & 1) * 64, wn = (wave >> 1) * 128;

  const unsigned short* Wg = Wb + (size_t)head * L_DIM * H_DIM;
  const int* rl = rowlist + head * B_ROWS;

  // per-thread staging sources (loop-invariant; +kt per iteration)
  const unsigned short* srcA[4];
  int ldsoA[4];
#pragma unroll
  for (int p = 0; p < 4; p++) {
    int c = p * 256 + t;                  // 16B chunk id 0..1023 (128 rows x 8)
    int row = c >> 3;
    int ks = ((c & 7) ^ (row & 7)) * 8;   // XOR-swizzled source column (shorts)
    int idx = rowbase + row;
    idx = idx < cntg ? idx : cntg - 1;    // clamp into valid rowlist entries
    srcA[p] = Hb + (size_t)rl[idx] * H_DIM + ks;
    ldsoA[p] = c * 8;                     // lane-linear LDS dst (shorts)
  }
  const unsigned short* srcB[8];
  int ldsoB[8];
#pragma unroll
  for (int p = 0; p < 8; p++) {
    int c = p * 256 + t;                  // 16B chunk id 0..2047 (256 rows x 8)
    int row = c >> 3;
    int ks = ((c & 7) ^ (row & 7)) * 8;
    srcB[p] = Wg + (size_t)(n0 + row) * H_DIM + ks;
    ldsoB[p] = c * 8;
  }

  f32x4 acc[4][8] = {};

  // prologue: stage tile 0
#pragma unroll
  for (int p = 0; p < 4; p++) load_lds16(srcA[p], &As[0][ldsoA[p]]);
#pragma unroll
  for (int p = 0; p < 8; p++) load_lds16(srcB[p], &Bs[0][ldsoB[p]]);
  __syncthreads();

  for (int kt = 0; kt < H_DIM; kt += 64) {
    const int cur = (kt >> 6) & 1;
    if (kt + 64 < H_DIM) {
      const int nxt = cur ^ 1;
#pragma unroll
      for (int p = 0; p < 4; p++) load_lds16(srcA[p] + kt + 64, &As[nxt][ldsoA[p]]);
#pragma unroll
      for (int p = 0; p < 8; p++) load_lds16(srcB[p] + kt + 64, &Bs[nxt][ldsoB[p]]);
    }
#pragma unroll
    for (int kk = 0; kk < 64; kk += 32) {
      bf16x8 af[4], bf[8];
      const int sw = c16 & 7;             // row&7 == c16&7 for all frag rows
      const int colb = (kk >> 4) << 1;    // kk=0 -> chunks 0..3, kk=32 -> 4..7
      const int cl = (colb + quad) ^ sw;
#pragma unroll
      for (int i = 0; i < 4; i++) {
        int row = wm + i * 16 + c16;
        af[i] = *(const bf16x8*)(&As[cur][row * 64 + cl * 8]);
      }
#pragma unroll
      for (int j = 0; j < 8; j++) {
        int row = wn + j * 16 + c16;
        bf[j] = *(const bf16x8*)(&Bs[cur][row * 64 + cl * 8]);
      }
#pragma unroll
      for (int i = 0; i < 4; i++)
#pragma unroll
        for (int j = 0; j < 8; j++)
          acc[i][j] = __builtin_amdgcn_mfma_f32_16x16x32_bf16(af[i], bf[j], acc[i][j], 0, 0, 0);
    }
    __syncthreads();   // drains prefetch vmcnt (overlapped with compute above)
  }

  // epilogue: C/D layout col=lane&15, row=quad*4+reg; scatter through rowlist, add bias
  float bv[8];
#pragma unroll
  for (int j = 0; j < 8; j++) bv[j] = bias[head * L_DIM + n0 + wn + j * 16 + c16];
#pragma unroll
  for (int i = 0; i < 4; i++) {
    int rloc0 = wm + i * 16 + quad * 4;
#pragma unroll
    for (int r = 0; r < 4; r++) {
      int idx = rloc0 + r;
      if (rowbase + idx < cntg) {
        int orow = rl[rowbase + idx];
        float* orowp = out + (size_t)orow * L_DIM + n0 + wn;
#pragma unroll
        for (int j = 0; j < 8; j++) {
          __builtin_nontemporal_store(acc[i][j][r] + bv[j], &orowp[j * 16 + c16]);
        }
      }
    }
  }
}

extern "C" void kernel_launch(void* const* d_in, const int* in_sizes, int n_in,
                              void* d_out, int out_size, void* d_ws, size_t ws_size,
                              hipStream_t stream) {
  const float* hidden = (const float*)d_in[0];
  const float* W      = (const float*)d_in[1];
  const float* bias   = (const float*)d_in[2];
  const int* group    = (const int*)d_in[3];
  const int* labels   = (const int*)d_in[4];
  float* out = (float*)d_out;

  // ws layout: [cnt 64B][rowlist 5*8192*4B @256][Wb bf16 @256KB][Hb bf16 after Wb]
  char* ws = (char*)d_ws;
  int* cnt = (int*)ws;
  int* rowlist = (int*)(ws + 256);
  unsigned short* Wb = (unsigned short*)(ws + (1 << 18));
  unsigned short* Hb = (unsigned short*)(ws + (1 << 18) + (size_t)NH * L_DIM * H_DIM * 2);

  hipMemsetAsync(cnt, 0, 64, stream);
  k_conv<<<1568, 256, 0, stream>>>(hidden, W, group, labels, cnt, rowlist, Hb, Wb, out);
  k_gemm<<<dim3(L_DIM / 256, B_ROWS / 128, NH), 256, 0, stream>>>(Hb, Wb, bias, cnt, rowlist, out);
}